// Round 4
// baseline (595.046 us; speedup 1.0000x reference)
//
#include <hip/hip_runtime.h>
#include <hip/hip_bf16.h>
#include <hip/hip_fp16.h>
#include <math.h>

#define NN 50000
#define NP 50048            // NN padded to 64-row tiles
#define NE 800000
#define ET (NE + NN)
#define DF 128
#define NH 4
#define HD 512
#define BN_EPS 1e-5f

typedef __hip_bfloat16 bf16;
typedef __attribute__((ext_vector_type(8))) short bf16x8;
typedef __attribute__((ext_vector_type(4))) float f32x4;

// raw-bits bf16 -> f32 (argument MUST be a genuine short, not __hip_bfloat16)
__device__ __forceinline__ float bf2f(short s) {
    return __uint_as_float(((unsigned)(unsigned short)s) << 16);
}

// ---------- input conversions ----------
__global__ __launch_bounds__(256) void cvt_x_bf16(const float* __restrict__ in, bf16* __restrict__ out) {
    int i = blockIdx.x * 256 + threadIdx.x;            // 4 elements per thread
    if (i >= NN * DF / 4) return;
    float4 v = reinterpret_cast<const float4*>(in)[i];
    union { bf16 b[4]; short4 s; } u;
    u.b[0] = __float2bfloat16(v.x); u.b[1] = __float2bfloat16(v.y);
    u.b[2] = __float2bfloat16(v.z); u.b[3] = __float2bfloat16(v.w);
    reinterpret_cast<short4*>(out)[i] = u.s;
}

// W [128,512] f32 -> Wt [512,128] bf16
__global__ __launch_bounds__(256) void cvt_wt(const float* __restrict__ W, bf16* __restrict__ Wt) {
    int i = blockIdx.x * 256 + threadIdx.x;
    if (i >= HD * DF) return;
    int c = i >> 7, k = i & 127;
    Wt[i] = __float2bfloat16(W[k * HD + c]);
}

// ---------- MFMA GEMM: Hout[M,512](bf16) = A[M,128](bf16) @ Wt[512,128]^T ----------
__global__ __launch_bounds__(256) void gemm_mfma(const bf16* __restrict__ A,
                                                 const bf16* __restrict__ Bt,
                                                 bf16* __restrict__ Hout, int M) {
    __shared__ __align__(16) char As[16384];   // [64 rows][128 k] bf16, XOR-swizzled
    __shared__ __align__(16) char Bs[16384];   // [64 cols][128 k] bf16, XOR-swizzled
    const int tid = threadIdx.x;
    const int m0 = blockIdx.x * 64;
    const int n0 = blockIdx.y * 64;
    const char* Ab = (const char*)(A + (size_t)m0 * DF);
    const char* Bb = (const char*)(Bt + (size_t)n0 * DF);
    #pragma unroll
    for (int i = 0; i < 4; ++i) {
        int d = (tid + i * 256) * 16;
        int s = d ^ (((d >> 8) & 7) << 4);
        __builtin_amdgcn_global_load_lds((const __attribute__((address_space(1))) void*)(Ab + s),
                                         (__attribute__((address_space(3))) void*)(As + d), 16, 0, 0);
    }
    #pragma unroll
    for (int i = 0; i < 4; ++i) {
        int d = (tid + i * 256) * 16;
        int s = d ^ (((d >> 8) & 7) << 4);
        __builtin_amdgcn_global_load_lds((const __attribute__((address_space(1))) void*)(Bb + s),
                                         (__attribute__((address_space(3))) void*)(Bs + d), 16, 0, 0);
    }
    __syncthreads();
    const int lane = tid & 63;
    const int wave = tid >> 6;
    const int wm = (wave & 1) * 32;
    const int wn = (wave >> 1) * 32;
    const int lr = lane & 15;
    const int lkb = (lane >> 4) * 16;
    f32x4 acc[2][2] = {};
    #pragma unroll
    for (int kk = 0; kk < 4; ++kk) {
        int kb = kk * 64 + lkb;
        int ra0 = wm + lr, ra1 = wm + 16 + lr;
        int rb0 = wn + lr, rb1 = wn + 16 + lr;
        bf16x8 a0 = *(const bf16x8*)(As + ((ra0 * 256 + kb) ^ ((ra0 & 7) << 4)));
        bf16x8 a1 = *(const bf16x8*)(As + ((ra1 * 256 + kb) ^ ((ra1 & 7) << 4)));
        bf16x8 b0 = *(const bf16x8*)(Bs + ((rb0 * 256 + kb) ^ ((rb0 & 7) << 4)));
        bf16x8 b1 = *(const bf16x8*)(Bs + ((rb1 * 256 + kb) ^ ((rb1 & 7) << 4)));
        acc[0][0] = __builtin_amdgcn_mfma_f32_16x16x32_bf16(a0, b0, acc[0][0], 0, 0, 0);
        acc[0][1] = __builtin_amdgcn_mfma_f32_16x16x32_bf16(a0, b1, acc[0][1], 0, 0, 0);
        acc[1][0] = __builtin_amdgcn_mfma_f32_16x16x32_bf16(a1, b0, acc[1][0], 0, 0, 0);
        acc[1][1] = __builtin_amdgcn_mfma_f32_16x16x32_bf16(a1, b1, acc[1][1], 0, 0, 0);
    }
    const int orow = (lane >> 4) * 4;
    #pragma unroll
    for (int mi = 0; mi < 2; ++mi) {
        #pragma unroll
        for (int r = 0; r < 4; ++r) {
            int gr = m0 + wm + mi * 16 + orow + r;
            if (gr < M) {
                #pragma unroll
                for (int ni = 0; ni < 2; ++ni)
                    Hout[(size_t)gr * HD + n0 + wn + ni * 16 + lr] = __float2bfloat16(acc[mi][ni][r]);
            }
        }
    }
}

// ---------- per-node attention scores: vectorized, 4 nodes / 256-block ----------
__global__ __launch_bounds__(256) void att_scores(const bf16* __restrict__ H,
                                                  const float* __restrict__ as,
                                                  const float* __restrict__ ad,
                                                  float* __restrict__ a_src,
                                                  float* __restrict__ a_dst) {
    const int n = blockIdx.x * 4 + (threadIdx.x >> 6);
    const int l = threadIdx.x & 63;           // lane owns elems l*8..l*8+7 (head = l>>4)
    bf16x8 hv = *reinterpret_cast<const bf16x8*>(H + (size_t)n * HD + l * 8);
    float4 s0 = reinterpret_cast<const float4*>(as)[l * 2];
    float4 s1 = reinterpret_cast<const float4*>(as)[l * 2 + 1];
    float4 d0 = reinterpret_cast<const float4*>(ad)[l * 2];
    float4 d1 = reinterpret_cast<const float4*>(ad)[l * 2 + 1];
    float hf[8];
    #pragma unroll
    for (int j = 0; j < 8; ++j) hf[j] = bf2f(hv[j]);
    float ps = hf[0]*s0.x + hf[1]*s0.y + hf[2]*s0.z + hf[3]*s0.w
             + hf[4]*s1.x + hf[5]*s1.y + hf[6]*s1.z + hf[7]*s1.w;
    float pd = hf[0]*d0.x + hf[1]*d0.y + hf[2]*d0.z + hf[3]*d0.w
             + hf[4]*d1.x + hf[5]*d1.y + hf[6]*d1.z + hf[7]*d1.w;
    #pragma unroll
    for (int off = 1; off < 16; off <<= 1) {
        ps += __shfl_xor(ps, off);
        pd += __shfl_xor(pd, off);
    }
    if ((l & 15) == 0) {
        a_src[n * NH + (l >> 4)] = ps;
        a_dst[n * NH + (l >> 4)] = pd;
    }
}

// ---------- CSR build ----------
__global__ void count_deg(const int* __restrict__ ei, int* __restrict__ counts) {
    int e = blockIdx.x * blockDim.x + threadIdx.x;
    if (e >= ET) return;
    int d = (e < NE) ? ei[NE + e] : (e - NE);
    atomicAdd(&counts[d], 1);
}

__global__ __launch_bounds__(256) void scan1(const int* __restrict__ counts, int* __restrict__ bsum) {
    __shared__ int sd[256];
    int i = blockIdx.x * 256 + threadIdx.x;
    sd[threadIdx.x] = (i < NN) ? counts[i] : 0;
    __syncthreads();
    for (int s = 128; s > 0; s >>= 1) {
        if (threadIdx.x < s) sd[threadIdx.x] += sd[threadIdx.x + s];
        __syncthreads();
    }
    if (threadIdx.x == 0) bsum[blockIdx.x] = sd[0];
}

__global__ void scan2(int* __restrict__ bsum, int nb) {
    if (threadIdx.x == 0 && blockIdx.x == 0) {
        int acc = 0;
        for (int i = 0; i < nb; ++i) { int v = bsum[i]; bsum[i] = acc; acc += v; }
    }
}

__global__ __launch_bounds__(256) void scan3(const int* __restrict__ counts, const int* __restrict__ bsum,
                                             int* __restrict__ row_ptr, int* __restrict__ cursor) {
    __shared__ int sd[256];
    int i = blockIdx.x * 256 + threadIdx.x;
    int v = (i < NN) ? counts[i] : 0;
    sd[threadIdx.x] = v;
    __syncthreads();
    for (int s = 1; s < 256; s <<= 1) {
        int t = sd[threadIdx.x];
        int u = (threadIdx.x >= s) ? sd[threadIdx.x - s] : 0;
        __syncthreads();
        sd[threadIdx.x] = t + u;
        __syncthreads();
    }
    int excl = sd[threadIdx.x] - v + bsum[blockIdx.x];
    if (i < NN) { row_ptr[i] = excl; cursor[i] = excl; }
    if (i == 0) row_ptr[NN] = ET;
}

__global__ void fill_csr(const int* __restrict__ ei, int* __restrict__ cursor, int* __restrict__ col) {
    int e = blockIdx.x * blockDim.x + threadIdx.x;
    if (e >= ET) return;
    int s, d;
    if (e < NE) { s = ei[e]; d = ei[NE + e]; } else { s = d = e - NE; }
    int pos = atomicAdd(&cursor[d], 1);
    col[pos] = s;
}

// ---------- per-edge alpha (one thread per dst node), packed fp16 ----------
// alpha[2j], alpha[2j+1] hold {h0,h1},{h2,h3}: 0.25 * exp(lg - m) / s
__global__ __launch_bounds__(256) void edge_alpha(const float* __restrict__ a_src,
                                                  const float* __restrict__ a_dst,
                                                  const int* __restrict__ row_ptr,
                                                  const int* __restrict__ col,
                                                  __half2* __restrict__ alpha) {
    int n = blockIdx.x * 256 + threadIdx.x;
    if (n >= NN) return;
    const float d0 = a_dst[n*4], d1 = a_dst[n*4+1], d2 = a_dst[n*4+2], d3 = a_dst[n*4+3];
    const int start = row_ptr[n], end = row_ptr[n + 1];
    float m0 = -1e30f, m1 = -1e30f, m2 = -1e30f, m3 = -1e30f;
    float s0 = 0.f, s1 = 0.f, s2 = 0.f, s3 = 0.f;
    for (int j = start; j < end; ++j) {
        int c = col[j] * 4;
        float l0 = a_src[c]   + d0; l0 = l0 > 0.f ? l0 : 0.2f * l0;
        float l1 = a_src[c+1] + d1; l1 = l1 > 0.f ? l1 : 0.2f * l1;
        float l2 = a_src[c+2] + d2; l2 = l2 > 0.f ? l2 : 0.2f * l2;
        float l3 = a_src[c+3] + d3; l3 = l3 > 0.f ? l3 : 0.2f * l3;
        float n0 = fmaxf(m0, l0); s0 = s0 * __expf(m0 - n0) + __expf(l0 - n0); m0 = n0;
        float n1 = fmaxf(m1, l1); s1 = s1 * __expf(m1 - n1) + __expf(l1 - n1); m1 = n1;
        float n2 = fmaxf(m2, l2); s2 = s2 * __expf(m2 - n2) + __expf(l2 - n2); m2 = n2;
        float n3 = fmaxf(m3, l3); s3 = s3 * __expf(m3 - n3) + __expf(l3 - n3); m3 = n3;
    }
    const float i0 = 0.25f / s0, i1 = 0.25f / s1, i2 = 0.25f / s2, i3 = 0.25f / s3;
    for (int j = start; j < end; ++j) {
        int c = col[j] * 4;
        float l0 = a_src[c]   + d0; l0 = l0 > 0.f ? l0 : 0.2f * l0;
        float l1 = a_src[c+1] + d1; l1 = l1 > 0.f ? l1 : 0.2f * l1;
        float l2 = a_src[c+2] + d2; l2 = l2 > 0.f ? l2 : 0.2f * l2;
        float l3 = a_src[c+3] + d3; l3 = l3 > 0.f ? l3 : 0.2f * l3;
        alpha[2*j]   = __floats2half2_rn(__expf(l0 - m0) * i0, __expf(l1 - m1) * i1);
        alpha[2*j+1] = __floats2half2_rn(__expf(l2 - m2) * i2, __expf(l3 - m3) * i3);
    }
}

// ---------- weighted gather-sum aggregation ----------
__global__ __launch_bounds__(64) void aggregate(const bf16* __restrict__ H,
                                                const __half2* __restrict__ alpha,
                                                const int* __restrict__ row_ptr,
                                                const int* __restrict__ col,
                                                const float* __restrict__ bias,
                                                float* __restrict__ out) {
    const int n = blockIdx.x;
    const int l = threadIdx.x;          // owns columns 2l, 2l+1
    const int start = row_ptr[n], end = row_ptr[n + 1];
    const unsigned* __restrict__ H4 = reinterpret_cast<const unsigned*>(H);  // bf16 pair per u32
    float ax = 0.f, ay = 0.f;
    #pragma unroll 2
    for (int j = start; j < end; ++j) {
        int s = col[j] * 256;
        float2 a01 = __half22float2(alpha[2*j]);
        float2 a23 = __half22float2(alpha[2*j+1]);
        unsigned u0 = H4[s + l];
        unsigned u1 = H4[s + 64 + l];
        unsigned u2 = H4[s + 128 + l];
        unsigned u3 = H4[s + 192 + l];
        ax += a01.x * __uint_as_float(u0 << 16) + a01.y * __uint_as_float(u1 << 16)
            + a23.x * __uint_as_float(u2 << 16) + a23.y * __uint_as_float(u3 << 16);
        ay += a01.x * __uint_as_float(u0 & 0xffff0000u) + a01.y * __uint_as_float(u1 & 0xffff0000u)
            + a23.x * __uint_as_float(u2 & 0xffff0000u) + a23.y * __uint_as_float(u3 & 0xffff0000u);
    }
    float2 b = reinterpret_cast<const float2*>(bias)[l];
    reinterpret_cast<float2*>(out)[n * 64 + l] = make_float2(ax + b.x, ay + b.y);
}

// ---------- BatchNorm ----------
__global__ __launch_bounds__(256) void bn_stats(const float* __restrict__ x, float* __restrict__ stats) {
    const int c = threadIdx.x & 127;
    const int half = threadIdx.x >> 7;
    float sum = 0.f, sq = 0.f;
    for (int r = blockIdx.x * 2 + half; r < NN; r += gridDim.x * 2) {
        float v = x[r * DF + c];
        sum += v; sq += v * v;
    }
    __shared__ float s1[256], s2[256];
    s1[threadIdx.x] = sum; s2[threadIdx.x] = sq;
    __syncthreads();
    if (threadIdx.x < 128) {
        atomicAdd(&stats[c], s1[threadIdx.x] + s1[threadIdx.x + 128]);
        atomicAdd(&stats[128 + c], s2[threadIdx.x] + s2[threadIdx.x + 128]);
    }
}

__global__ __launch_bounds__(256) void bn_apply_bf16(const float* __restrict__ x, const float* __restrict__ stats,
                                                     const float* __restrict__ gamma, const float* __restrict__ beta,
                                                     bf16* __restrict__ out) {
    int i = blockIdx.x * blockDim.x + threadIdx.x;
    if (i >= NN * DF) return;
    int c = i & 127;
    float mu = stats[c] * (1.f / NN);
    float var = stats[128 + c] * (1.f / NN) - mu * mu;
    float v = (x[i] - mu) * rsqrtf(var + BN_EPS) * gamma[c] + beta[c];
    out[i] = __float2bfloat16(fmaxf(v, 0.f));
}

__global__ __launch_bounds__(256) void bn_apply(const float* __restrict__ x, const float* __restrict__ stats,
                                                const float* __restrict__ gamma, const float* __restrict__ beta,
                                                float* __restrict__ out) {
    int i = blockIdx.x * blockDim.x + threadIdx.x;
    if (i >= NN * DF) return;
    int c = i & 127;
    float mu = stats[c] * (1.f / NN);
    float var = stats[128 + c] * (1.f / NN) - mu * mu;
    float v = (x[i] - mu) * rsqrtf(var + BN_EPS) * gamma[c] + beta[c];
    out[i] = fmaxf(v, 0.f);
}

extern "C" void kernel_launch(void* const* d_in, const int* in_sizes, int n_in,
                              void* d_out, int out_size, void* d_ws, size_t ws_size,
                              hipStream_t stream) {
    (void)in_sizes; (void)n_in; (void)out_size; (void)ws_size;
    const float* x   = (const float*)d_in[0];
    const int*   ei  = (const int*)d_in[1];
    const float* W1  = (const float*)d_in[2];
    const float* as1 = (const float*)d_in[3];
    const float* ad1 = (const float*)d_in[4];
    const float* b1  = (const float*)d_in[5];
    const float* g1  = (const float*)d_in[6];
    const float* be1 = (const float*)d_in[7];
    const float* W2  = (const float*)d_in[8];
    const float* as2 = (const float*)d_in[9];
    const float* ad2 = (const float*)d_in[10];
    const float* b2  = (const float*)d_in[11];
    const float* g2  = (const float*)d_in[12];
    const float* be2 = (const float*)d_in[13];
    float* out = (float*)d_out;

    char* ws = (char*)d_ws;
    size_t off = 0;
    auto alloc = [&](size_t bytes) -> void* {
        void* p = ws + off;
        off += (bytes + 255) & ~(size_t)255;
        return p;
    };
    bf16*   h       = (bf16*)alloc((size_t)NN * HD * 2);      // 51.2 MB
    bf16*   xb      = (bf16*)alloc((size_t)NP * DF * 2);      // 12.8 MB (padded)
    bf16*   Wt1     = (bf16*)alloc((size_t)HD * DF * 2);
    bf16*   Wt2     = (bf16*)alloc((size_t)HD * DF * 2);
    float*  a_src   = (float*)alloc((size_t)NN * NH * 4);
    float*  a_dst   = (float*)alloc((size_t)NN * NH * 4);
    int*    row_ptr = (int*)alloc((size_t)(NN + 1) * 4);
    int*    cursor  = (int*)alloc((size_t)NN * 4);
    int*    counts  = (int*)alloc((size_t)NN * 4);
    int*    bsum    = (int*)alloc(256 * 4);
    int*    colidx  = (int*)alloc((size_t)ET * 4);
    __half2* alpha  = (__half2*)alloc((size_t)ET * 8);        // 6.8 MB (fp16 x4 per edge)
    float*  agg     = (float*)alloc((size_t)NN * DF * 4);     // 25.6 MB
    float*  stats   = (float*)alloc(256 * 4);
    // high-water ~102.3 MB (R1 proved >=107.4 MB available)

    const int NB = (NN + 255) / 256;        // 196
    const int EB = (ET + 255) / 256;        // 3321
    dim3 ggrid(NP / 64, HD / 64);           // 782 x 8

    // ---- dtype prep + CSR build ----
    cvt_x_bf16<<<(NN * DF / 4 + 255) / 256, 256, 0, stream>>>(x, xb);
    cvt_wt<<<(HD * DF + 255) / 256, 256, 0, stream>>>(W1, Wt1);
    cvt_wt<<<(HD * DF + 255) / 256, 256, 0, stream>>>(W2, Wt2);
    hipMemsetAsync(counts, 0, (size_t)NN * 4, stream);
    count_deg<<<EB, 256, 0, stream>>>(ei, counts);
    scan1<<<NB, 256, 0, stream>>>(counts, bsum);
    scan2<<<1, 64, 0, stream>>>(bsum, NB);
    scan3<<<NB, 256, 0, stream>>>(counts, bsum, row_ptr, cursor);
    fill_csr<<<EB, 256, 0, stream>>>(ei, cursor, colidx);

    // ---- layer 1 ----
    gemm_mfma<<<ggrid, 256, 0, stream>>>(xb, Wt1, h, NN);
    att_scores<<<NN / 4, 256, 0, stream>>>(h, as1, ad1, a_src, a_dst);
    edge_alpha<<<NB, 256, 0, stream>>>(a_src, a_dst, row_ptr, colidx, alpha);
    aggregate<<<NN, 64, 0, stream>>>(h, alpha, row_ptr, colidx, b1, agg);
    hipMemsetAsync(stats, 0, 256 * 4, stream);
    bn_stats<<<200, 256, 0, stream>>>(agg, stats);
    bn_apply_bf16<<<(NN * DF + 255) / 256, 256, 0, stream>>>(agg, stats, g1, be1, xb);

    // ---- layer 2 ----
    gemm_mfma<<<ggrid, 256, 0, stream>>>(xb, Wt2, h, NN);
    att_scores<<<NN / 4, 256, 0, stream>>>(h, as2, ad2, a_src, a_dst);
    edge_alpha<<<NB, 256, 0, stream>>>(a_src, a_dst, row_ptr, colidx, alpha);
    aggregate<<<NN, 64, 0, stream>>>(h, alpha, row_ptr, colidx, b2, agg);
    hipMemsetAsync(stats, 0, 256 * 4, stream);
    bn_stats<<<200, 256, 0, stream>>>(agg, stats);
    bn_apply<<<(NN * DF + 255) / 256, 256, 0, stream>>>(agg, stats, g2, be2, out);
}

// Round 5
// 576.596 us; speedup vs baseline: 1.0320x; 1.0320x over previous
//
#include <hip/hip_runtime.h>
#include <hip/hip_bf16.h>
#include <hip/hip_fp16.h>
#include <math.h>

#define NN 50000
#define NP 50048            // NN padded to 64-row tiles
#define NE 800000
#define ET (NE + NN)
#define DF 128
#define NH 4
#define HD 512
#define BN_EPS 1e-5f

typedef __hip_bfloat16 bf16;
typedef __attribute__((ext_vector_type(8))) short bf16x8;
typedef __attribute__((ext_vector_type(4))) float f32x4;

// raw-bits bf16 -> f32 (argument MUST be a genuine short, not __hip_bfloat16)
__device__ __forceinline__ float bf2f(short s) {
    return __uint_as_float(((unsigned)(unsigned short)s) << 16);
}

// ---------- input conversions ----------
__global__ __launch_bounds__(256) void cvt_x_bf16(const float* __restrict__ in, bf16* __restrict__ out) {
    int i = blockIdx.x * 256 + threadIdx.x;            // 4 elements per thread
    if (i >= NN * DF / 4) return;
    float4 v = reinterpret_cast<const float4*>(in)[i];
    union { bf16 b[4]; short4 s; } u;
    u.b[0] = __float2bfloat16(v.x); u.b[1] = __float2bfloat16(v.y);
    u.b[2] = __float2bfloat16(v.z); u.b[3] = __float2bfloat16(v.w);
    reinterpret_cast<short4*>(out)[i] = u.s;
}

// W [128,512] f32 -> Wt [512,128] bf16
__global__ __launch_bounds__(256) void cvt_wt(const float* __restrict__ W, bf16* __restrict__ Wt) {
    int i = blockIdx.x * 256 + threadIdx.x;
    if (i >= HD * DF) return;
    int c = i >> 7, k = i & 127;
    Wt[i] = __float2bfloat16(W[k * HD + c]);
}

// ---------- MFMA GEMM: Hout[M,512](bf16) = A[M,128](bf16) @ Wt[512,128]^T ----------
__global__ __launch_bounds__(256) void gemm_mfma(const bf16* __restrict__ A,
                                                 const bf16* __restrict__ Bt,
                                                 bf16* __restrict__ Hout, int M) {
    __shared__ __align__(16) char As[16384];   // [64 rows][128 k] bf16, XOR-swizzled
    __shared__ __align__(16) char Bs[16384];   // [64 cols][128 k] bf16, XOR-swizzled
    const int tid = threadIdx.x;
    const int m0 = blockIdx.x * 64;
    const int n0 = blockIdx.y * 64;
    const char* Ab = (const char*)(A + (size_t)m0 * DF);
    const char* Bb = (const char*)(Bt + (size_t)n0 * DF);
    #pragma unroll
    for (int i = 0; i < 4; ++i) {
        int d = (tid + i * 256) * 16;
        int s = d ^ (((d >> 8) & 7) << 4);
        __builtin_amdgcn_global_load_lds((const __attribute__((address_space(1))) void*)(Ab + s),
                                         (__attribute__((address_space(3))) void*)(As + d), 16, 0, 0);
    }
    #pragma unroll
    for (int i = 0; i < 4; ++i) {
        int d = (tid + i * 256) * 16;
        int s = d ^ (((d >> 8) & 7) << 4);
        __builtin_amdgcn_global_load_lds((const __attribute__((address_space(1))) void*)(Bb + s),
                                         (__attribute__((address_space(3))) void*)(Bs + d), 16, 0, 0);
    }
    __syncthreads();
    const int lane = tid & 63;
    const int wave = tid >> 6;
    const int wm = (wave & 1) * 32;
    const int wn = (wave >> 1) * 32;
    const int lr = lane & 15;
    const int lkb = (lane >> 4) * 16;
    f32x4 acc[2][2] = {};
    #pragma unroll
    for (int kk = 0; kk < 4; ++kk) {
        int kb = kk * 64 + lkb;
        int ra0 = wm + lr, ra1 = wm + 16 + lr;
        int rb0 = wn + lr, rb1 = wn + 16 + lr;
        bf16x8 a0 = *(const bf16x8*)(As + ((ra0 * 256 + kb) ^ ((ra0 & 7) << 4)));
        bf16x8 a1 = *(const bf16x8*)(As + ((ra1 * 256 + kb) ^ ((ra1 & 7) << 4)));
        bf16x8 b0 = *(const bf16x8*)(Bs + ((rb0 * 256 + kb) ^ ((rb0 & 7) << 4)));
        bf16x8 b1 = *(const bf16x8*)(Bs + ((rb1 * 256 + kb) ^ ((rb1 & 7) << 4)));
        acc[0][0] = __builtin_amdgcn_mfma_f32_16x16x32_bf16(a0, b0, acc[0][0], 0, 0, 0);
        acc[0][1] = __builtin_amdgcn_mfma_f32_16x16x32_bf16(a0, b1, acc[0][1], 0, 0, 0);
        acc[1][0] = __builtin_amdgcn_mfma_f32_16x16x32_bf16(a1, b0, acc[1][0], 0, 0, 0);
        acc[1][1] = __builtin_amdgcn_mfma_f32_16x16x32_bf16(a1, b1, acc[1][1], 0, 0, 0);
    }
    const int orow = (lane >> 4) * 4;
    #pragma unroll
    for (int mi = 0; mi < 2; ++mi) {
        #pragma unroll
        for (int r = 0; r < 4; ++r) {
            int gr = m0 + wm + mi * 16 + orow + r;
            if (gr < M) {
                #pragma unroll
                for (int ni = 0; ni < 2; ++ni)
                    Hout[(size_t)gr * HD + n0 + wn + ni * 16 + lr] = __float2bfloat16(acc[mi][ni][r]);
            }
        }
    }
}

// ---------- per-node attention scores: vectorized, 4 nodes / 256-block ----------
__global__ __launch_bounds__(256) void att_scores(const bf16* __restrict__ H,
                                                  const float* __restrict__ as,
                                                  const float* __restrict__ ad,
                                                  float* __restrict__ a_src,
                                                  float* __restrict__ a_dst) {
    const int n = blockIdx.x * 4 + (threadIdx.x >> 6);
    const int l = threadIdx.x & 63;           // lane owns elems l*8..l*8+7 (head = l>>4)
    bf16x8 hv = *reinterpret_cast<const bf16x8*>(H + (size_t)n * HD + l * 8);
    float4 s0 = reinterpret_cast<const float4*>(as)[l * 2];
    float4 s1 = reinterpret_cast<const float4*>(as)[l * 2 + 1];
    float4 d0 = reinterpret_cast<const float4*>(ad)[l * 2];
    float4 d1 = reinterpret_cast<const float4*>(ad)[l * 2 + 1];
    float hf[8];
    #pragma unroll
    for (int j = 0; j < 8; ++j) hf[j] = bf2f(hv[j]);
    float ps = hf[0]*s0.x + hf[1]*s0.y + hf[2]*s0.z + hf[3]*s0.w
             + hf[4]*s1.x + hf[5]*s1.y + hf[6]*s1.z + hf[7]*s1.w;
    float pd = hf[0]*d0.x + hf[1]*d0.y + hf[2]*d0.z + hf[3]*d0.w
             + hf[4]*d1.x + hf[5]*d1.y + hf[6]*d1.z + hf[7]*d1.w;
    #pragma unroll
    for (int off = 1; off < 16; off <<= 1) {
        ps += __shfl_xor(ps, off);
        pd += __shfl_xor(pd, off);
    }
    if ((l & 15) == 0) {
        a_src[n * NH + (l >> 4)] = ps;
        a_dst[n * NH + (l >> 4)] = pd;
    }
}

// ---------- CSR build ----------
__global__ void count_deg(const int* __restrict__ ei, int* __restrict__ counts) {
    int e = blockIdx.x * blockDim.x + threadIdx.x;
    if (e >= ET) return;
    int d = (e < NE) ? ei[NE + e] : (e - NE);
    atomicAdd(&counts[d], 1);
}

__global__ __launch_bounds__(256) void scan1(const int* __restrict__ counts, int* __restrict__ bsum) {
    __shared__ int sd[256];
    int i = blockIdx.x * 256 + threadIdx.x;
    sd[threadIdx.x] = (i < NN) ? counts[i] : 0;
    __syncthreads();
    for (int s = 128; s > 0; s >>= 1) {
        if (threadIdx.x < s) sd[threadIdx.x] += sd[threadIdx.x + s];
        __syncthreads();
    }
    if (threadIdx.x == 0) bsum[blockIdx.x] = sd[0];
}

__global__ void scan2(int* __restrict__ bsum, int nb) {
    if (threadIdx.x == 0 && blockIdx.x == 0) {
        int acc = 0;
        for (int i = 0; i < nb; ++i) { int v = bsum[i]; bsum[i] = acc; acc += v; }
    }
}

__global__ __launch_bounds__(256) void scan3(const int* __restrict__ counts, const int* __restrict__ bsum,
                                             int* __restrict__ row_ptr, int* __restrict__ cursor) {
    __shared__ int sd[256];
    int i = blockIdx.x * 256 + threadIdx.x;
    int v = (i < NN) ? counts[i] : 0;
    sd[threadIdx.x] = v;
    __syncthreads();
    for (int s = 1; s < 256; s <<= 1) {
        int t = sd[threadIdx.x];
        int u = (threadIdx.x >= s) ? sd[threadIdx.x - s] : 0;
        __syncthreads();
        sd[threadIdx.x] = t + u;
        __syncthreads();
    }
    int excl = sd[threadIdx.x] - v + bsum[blockIdx.x];
    if (i < NN) { row_ptr[i] = excl; cursor[i] = excl; }
    if (i == 0) row_ptr[NN] = ET;
}

__global__ void fill_csr(const int* __restrict__ ei, int* __restrict__ cursor, int* __restrict__ col) {
    int e = blockIdx.x * blockDim.x + threadIdx.x;
    if (e >= ET) return;
    int s, d;
    if (e < NE) { s = ei[e]; d = ei[NE + e]; } else { s = d = e - NE; }
    int pos = atomicAdd(&cursor[d], 1);
    col[pos] = s;
}

// ---------- per-edge alpha: one lane per (node, head) ----------
// alpha[4j+h] = fp16( 0.25 * exp(lg - m) / s )
__global__ __launch_bounds__(256) void edge_alpha(const float* __restrict__ a_src,
                                                  const float* __restrict__ a_dst,
                                                  const int* __restrict__ row_ptr,
                                                  const int* __restrict__ col,
                                                  __half* __restrict__ alpha) {
    int t = blockIdx.x * 256 + threadIdx.x;
    int n = t >> 2, h = t & 3;
    if (n >= NN) return;
    const float d = a_dst[n * 4 + h];
    const int start = row_ptr[n], end = row_ptr[n + 1];
    float m = -1e30f, s = 0.f;
    for (int j = start; j < end; ++j) {
        float a = a_src[col[j] * 4 + h] + d;
        a = a > 0.f ? a : 0.2f * a;
        float nm = fmaxf(m, a);
        s = s * __expf(m - nm) + __expf(a - nm);
        m = nm;
    }
    const float inv = 0.25f / s;
    for (int j = start; j < end; ++j) {
        float a = a_src[col[j] * 4 + h] + d;
        a = a > 0.f ? a : 0.2f * a;
        alpha[4 * j + h] = __float2half(__expf(a - m) * inv);
    }
}

// ---------- weighted gather-sum aggregation: 4 nodes / 256-block, unroll-4 ----------
struct alignas(8) h2x2 { __half2 a, b; };

__global__ __launch_bounds__(256) void aggregate(const bf16* __restrict__ H,
                                                 const __half* __restrict__ alpha,
                                                 const int* __restrict__ row_ptr,
                                                 const int* __restrict__ col,
                                                 const float* __restrict__ bias,
                                                 float* __restrict__ out) {
    const int n = blockIdx.x * 4 + (threadIdx.x >> 6);
    const int l = threadIdx.x & 63;          // owns columns 2l, 2l+1
    const int start = row_ptr[n], end = row_ptr[n + 1];
    const unsigned* __restrict__ H4 = reinterpret_cast<const unsigned*>(H);  // bf16 pair per u32
    const h2x2* __restrict__ A4 = reinterpret_cast<const h2x2*>(alpha);
    float ax = 0.f, ay = 0.f;
    int j = start;
    for (; j + 4 <= end; j += 4) {
        int s0 = col[j] * 256, s1 = col[j+1] * 256, s2 = col[j+2] * 256, s3 = col[j+3] * 256;
        h2x2 p0 = A4[j], p1 = A4[j+1], p2 = A4[j+2], p3 = A4[j+3];
        unsigned u00 = H4[s0 + l], u01 = H4[s0 + 64 + l], u02 = H4[s0 + 128 + l], u03 = H4[s0 + 192 + l];
        unsigned u10 = H4[s1 + l], u11 = H4[s1 + 64 + l], u12 = H4[s1 + 128 + l], u13 = H4[s1 + 192 + l];
        unsigned u20 = H4[s2 + l], u21 = H4[s2 + 64 + l], u22 = H4[s2 + 128 + l], u23 = H4[s2 + 192 + l];
        unsigned u30 = H4[s3 + l], u31 = H4[s3 + 64 + l], u32 = H4[s3 + 128 + l], u33 = H4[s3 + 192 + l];
        float2 a0 = __half22float2(p0.a), b0 = __half22float2(p0.b);
        float2 a1 = __half22float2(p1.a), b1 = __half22float2(p1.b);
        float2 a2 = __half22float2(p2.a), b2 = __half22float2(p2.b);
        float2 a3 = __half22float2(p3.a), b3 = __half22float2(p3.b);
        ax += a0.x * __uint_as_float(u00 << 16) + a0.y * __uint_as_float(u01 << 16)
            + b0.x * __uint_as_float(u02 << 16) + b0.y * __uint_as_float(u03 << 16);
        ay += a0.x * __uint_as_float(u00 & 0xffff0000u) + a0.y * __uint_as_float(u01 & 0xffff0000u)
            + b0.x * __uint_as_float(u02 & 0xffff0000u) + b0.y * __uint_as_float(u03 & 0xffff0000u);
        ax += a1.x * __uint_as_float(u10 << 16) + a1.y * __uint_as_float(u11 << 16)
            + b1.x * __uint_as_float(u12 << 16) + b1.y * __uint_as_float(u13 << 16);
        ay += a1.x * __uint_as_float(u10 & 0xffff0000u) + a1.y * __uint_as_float(u11 & 0xffff0000u)
            + b1.x * __uint_as_float(u12 & 0xffff0000u) + b1.y * __uint_as_float(u13 & 0xffff0000u);
        ax += a2.x * __uint_as_float(u20 << 16) + a2.y * __uint_as_float(u21 << 16)
            + b2.x * __uint_as_float(u22 << 16) + b2.y * __uint_as_float(u23 << 16);
        ay += a2.x * __uint_as_float(u20 & 0xffff0000u) + a2.y * __uint_as_float(u21 & 0xffff0000u)
            + b2.x * __uint_as_float(u22 & 0xffff0000u) + b2.y * __uint_as_float(u23 & 0xffff0000u);
        ax += a3.x * __uint_as_float(u30 << 16) + a3.y * __uint_as_float(u31 << 16)
            + b3.x * __uint_as_float(u32 << 16) + b3.y * __uint_as_float(u33 << 16);
        ay += a3.x * __uint_as_float(u30 & 0xffff0000u) + a3.y * __uint_as_float(u31 & 0xffff0000u)
            + b3.x * __uint_as_float(u32 & 0xffff0000u) + b3.y * __uint_as_float(u33 & 0xffff0000u);
    }
    for (; j < end; ++j) {
        int s0 = col[j] * 256;
        h2x2 p0 = A4[j];
        unsigned u00 = H4[s0 + l], u01 = H4[s0 + 64 + l], u02 = H4[s0 + 128 + l], u03 = H4[s0 + 192 + l];
        float2 a0 = __half22float2(p0.a), b0 = __half22float2(p0.b);
        ax += a0.x * __uint_as_float(u00 << 16) + a0.y * __uint_as_float(u01 << 16)
            + b0.x * __uint_as_float(u02 << 16) + b0.y * __uint_as_float(u03 << 16);
        ay += a0.x * __uint_as_float(u00 & 0xffff0000u) + a0.y * __uint_as_float(u01 & 0xffff0000u)
            + b0.x * __uint_as_float(u02 & 0xffff0000u) + b0.y * __uint_as_float(u03 & 0xffff0000u);
    }
    float2 b = reinterpret_cast<const float2*>(bias)[l];
    reinterpret_cast<float2*>(out)[n * 64 + l] = make_float2(ax + b.x, ay + b.y);
}

// ---------- BatchNorm ----------
__global__ __launch_bounds__(256) void bn_stats(const float* __restrict__ x, float* __restrict__ stats) {
    const int c = threadIdx.x & 127;
    const int half = threadIdx.x >> 7;
    float sum = 0.f, sq = 0.f;
    for (int r = blockIdx.x * 2 + half; r < NN; r += gridDim.x * 2) {
        float v = x[r * DF + c];
        sum += v; sq += v * v;
    }
    __shared__ float s1[256], s2[256];
    s1[threadIdx.x] = sum; s2[threadIdx.x] = sq;
    __syncthreads();
    if (threadIdx.x < 128) {
        atomicAdd(&stats[c], s1[threadIdx.x] + s1[threadIdx.x + 128]);
        atomicAdd(&stats[128 + c], s2[threadIdx.x] + s2[threadIdx.x + 128]);
    }
}

__global__ __launch_bounds__(256) void bn_apply_bf16(const float* __restrict__ x, const float* __restrict__ stats,
                                                     const float* __restrict__ gamma, const float* __restrict__ beta,
                                                     bf16* __restrict__ out) {
    int i = blockIdx.x * blockDim.x + threadIdx.x;
    if (i >= NN * DF) return;
    int c = i & 127;
    float mu = stats[c] * (1.f / NN);
    float var = stats[128 + c] * (1.f / NN) - mu * mu;
    float v = (x[i] - mu) * rsqrtf(var + BN_EPS) * gamma[c] + beta[c];
    out[i] = __float2bfloat16(fmaxf(v, 0.f));
}

__global__ __launch_bounds__(256) void bn_apply(const float* __restrict__ x, const float* __restrict__ stats,
                                                const float* __restrict__ gamma, const float* __restrict__ beta,
                                                float* __restrict__ out) {
    int i = blockIdx.x * blockDim.x + threadIdx.x;
    if (i >= NN * DF) return;
    int c = i & 127;
    float mu = stats[c] * (1.f / NN);
    float var = stats[128 + c] * (1.f / NN) - mu * mu;
    float v = (x[i] - mu) * rsqrtf(var + BN_EPS) * gamma[c] + beta[c];
    out[i] = fmaxf(v, 0.f);
}

extern "C" void kernel_launch(void* const* d_in, const int* in_sizes, int n_in,
                              void* d_out, int out_size, void* d_ws, size_t ws_size,
                              hipStream_t stream) {
    (void)in_sizes; (void)n_in; (void)out_size; (void)ws_size;
    const float* x   = (const float*)d_in[0];
    const int*   ei  = (const int*)d_in[1];
    const float* W1  = (const float*)d_in[2];
    const float* as1 = (const float*)d_in[3];
    const float* ad1 = (const float*)d_in[4];
    const float* b1  = (const float*)d_in[5];
    const float* g1  = (const float*)d_in[6];
    const float* be1 = (const float*)d_in[7];
    const float* W2  = (const float*)d_in[8];
    const float* as2 = (const float*)d_in[9];
    const float* ad2 = (const float*)d_in[10];
    const float* b2  = (const float*)d_in[11];
    const float* g2  = (const float*)d_in[12];
    const float* be2 = (const float*)d_in[13];
    float* out = (float*)d_out;

    char* ws = (char*)d_ws;
    size_t off = 0;
    auto alloc = [&](size_t bytes) -> void* {
        void* p = ws + off;
        off += (bytes + 255) & ~(size_t)255;
        return p;
    };
    bf16*   h       = (bf16*)alloc((size_t)NN * HD * 2);      // 51.2 MB
    bf16*   xb      = (bf16*)alloc((size_t)NP * DF * 2);      // 12.8 MB (padded)
    bf16*   Wt1     = (bf16*)alloc((size_t)HD * DF * 2);
    bf16*   Wt2     = (bf16*)alloc((size_t)HD * DF * 2);
    float*  a_src   = (float*)alloc((size_t)NN * NH * 4);
    float*  a_dst   = (float*)alloc((size_t)NN * NH * 4);
    int*    row_ptr = (int*)alloc((size_t)(NN + 1) * 4);
    int*    cursor  = (int*)alloc((size_t)NN * 4);
    int*    counts  = (int*)alloc((size_t)NN * 4);
    int*    bsum    = (int*)alloc(256 * 4);
    int*    colidx  = (int*)alloc((size_t)ET * 4);
    __half* alpha   = (__half*)alloc((size_t)ET * 8);         // 6.8 MB (fp16 x4 per edge)
    float*  agg     = (float*)alloc((size_t)NN * DF * 4);     // 25.6 MB
    float*  stats   = (float*)alloc(256 * 4);
    // high-water ~102.3 MB (R1 proved >=107.4 MB available)

    const int NB = (NN + 255) / 256;        // 196
    const int EB = (ET + 255) / 256;        // 3321
    dim3 ggrid(NP / 64, HD / 64);           // 782 x 8

    // ---- dtype prep + CSR build ----
    cvt_x_bf16<<<(NN * DF / 4 + 255) / 256, 256, 0, stream>>>(x, xb);
    cvt_wt<<<(HD * DF + 255) / 256, 256, 0, stream>>>(W1, Wt1);
    cvt_wt<<<(HD * DF + 255) / 256, 256, 0, stream>>>(W2, Wt2);
    hipMemsetAsync(counts, 0, (size_t)NN * 4, stream);
    count_deg<<<EB, 256, 0, stream>>>(ei, counts);
    scan1<<<NB, 256, 0, stream>>>(counts, bsum);
    scan2<<<1, 64, 0, stream>>>(bsum, NB);
    scan3<<<NB, 256, 0, stream>>>(counts, bsum, row_ptr, cursor);
    fill_csr<<<EB, 256, 0, stream>>>(ei, cursor, colidx);

    // ---- layer 1 ----
    gemm_mfma<<<ggrid, 256, 0, stream>>>(xb, Wt1, h, NN);
    att_scores<<<NN / 4, 256, 0, stream>>>(h, as1, ad1, a_src, a_dst);
    edge_alpha<<<(NN * 4 + 255) / 256, 256, 0, stream>>>(a_src, a_dst, row_ptr, colidx, alpha);
    aggregate<<<NN / 4, 256, 0, stream>>>(h, alpha, row_ptr, colidx, b1, agg);
    hipMemsetAsync(stats, 0, 256 * 4, stream);
    bn_stats<<<200, 256, 0, stream>>>(agg, stats);
    bn_apply_bf16<<<(NN * DF + 255) / 256, 256, 0, stream>>>(agg, stats, g1, be1, xb);

    // ---- layer 2 ----
    gemm_mfma<<<ggrid, 256, 0, stream>>>(xb, Wt2, h, NN);
    att_scores<<<NN / 4, 256, 0, stream>>>(h, as2, ad2, a_src, a_dst);
    edge_alpha<<<(NN * 4 + 255) / 256, 256, 0, stream>>>(a_src, a_dst, row_ptr, colidx, alpha);
    aggregate<<<NN / 4, 256, 0, stream>>>(h, alpha, row_ptr, colidx, b2, agg);
    hipMemsetAsync(stats, 0, 256 * 4, stream);
    bn_stats<<<200, 256, 0, stream>>>(agg, stats);
    bn_apply<<<(NN * DF + 255) / 256, 256, 0, stream>>>(agg, stats, g2, be2, out);
}

// Round 6
// 569.424 us; speedup vs baseline: 1.0450x; 1.0126x over previous
//
#include <hip/hip_runtime.h>
#include <hip/hip_bf16.h>
#include <hip/hip_fp16.h>
#include <math.h>

#define NN 50000
#define NP 50048            // NN padded to 64-row tiles
#define NE 800000
#define ET (NE + NN)
#define DF 128
#define NH 4
#define HD 512
#define BN_EPS 1e-5f

typedef __hip_bfloat16 bf16;
typedef __attribute__((ext_vector_type(8))) short bf16x8;
typedef __attribute__((ext_vector_type(4))) float f32x4;

// raw-bits bf16 -> f32 (argument MUST be a genuine short, not __hip_bfloat16)
__device__ __forceinline__ float bf2f(short s) {
    return __uint_as_float(((unsigned)(unsigned short)s) << 16);
}

// ---------- input conversions ----------
__global__ __launch_bounds__(256) void cvt_x_bf16(const float* __restrict__ in, bf16* __restrict__ out) {
    int i = blockIdx.x * 256 + threadIdx.x;            // 4 elements per thread
    if (i >= NN * DF / 4) return;
    float4 v = reinterpret_cast<const float4*>(in)[i];
    union { bf16 b[4]; short4 s; } u;
    u.b[0] = __float2bfloat16(v.x); u.b[1] = __float2bfloat16(v.y);
    u.b[2] = __float2bfloat16(v.z); u.b[3] = __float2bfloat16(v.w);
    reinterpret_cast<short4*>(out)[i] = u.s;
}

// W [128,512] f32 -> Wt [512,128] bf16 (both weight matrices in one launch)
__global__ __launch_bounds__(256) void cvt_wt2(const float* __restrict__ W1, const float* __restrict__ W2,
                                               bf16* __restrict__ Wt1, bf16* __restrict__ Wt2) {
    int i = blockIdx.x * 256 + threadIdx.x;
    if (i >= 2 * HD * DF) return;
    const float* W = (i < HD * DF) ? W1 : W2;
    bf16* Wt = (i < HD * DF) ? Wt1 : Wt2;
    int ii = (i < HD * DF) ? i : i - HD * DF;
    int c = ii >> 7, k = ii & 127;
    Wt[ii] = __float2bfloat16(W[k * HD + c]);
}

// ---------- MFMA GEMM: Hout[M,512](bf16) = A[M,128](bf16) @ Wt[512,128]^T ----------
// One block per 64-row A-panel; loops over all 8 column tiles with A staged once,
// B double-buffered (stage t+1 overlaps MFMA+store of t).
__global__ __launch_bounds__(256) void gemm_mfma(const bf16* __restrict__ A,
                                                 const bf16* __restrict__ Bt,
                                                 bf16* __restrict__ Hout, int M) {
    __shared__ __align__(16) char As[16384];      // [64 rows][128 k] bf16, XOR-swizzled
    __shared__ __align__(16) char Bs[2][16384];
    const int tid = threadIdx.x;
    const int m0 = blockIdx.x * 64;
    const char* Ab = (const char*)(A + (size_t)m0 * DF);
    // linear LDS dest + inverse-swizzled global source (Guideline 21)
    #pragma unroll
    for (int i = 0; i < 4; ++i) {
        int d = (tid + i * 256) * 16;
        int s = d ^ (((d >> 8) & 7) << 4);
        __builtin_amdgcn_global_load_lds((const __attribute__((address_space(1))) void*)(Ab + s),
                                         (__attribute__((address_space(3))) void*)(As + d), 16, 0, 0);
    }
    {
        const char* Bb = (const char*)Bt;
        #pragma unroll
        for (int i = 0; i < 4; ++i) {
            int d = (tid + i * 256) * 16;
            int s = d ^ (((d >> 8) & 7) << 4);
            __builtin_amdgcn_global_load_lds((const __attribute__((address_space(1))) void*)(Bb + s),
                                             (__attribute__((address_space(3))) void*)(Bs[0] + d), 16, 0, 0);
        }
    }
    const int lane = tid & 63;
    const int wave = tid >> 6;
    const int wm = (wave & 1) * 32;
    const int wn = (wave >> 1) * 32;
    const int lr = lane & 15;
    const int lkb = (lane >> 4) * 16;
    const int orow = (lane >> 4) * 4;
    for (int t = 0; t < 8; ++t) {
        __syncthreads();                       // staging for tile t complete; all reads of t-1 done
        if (t < 7) {
            const char* Bb = (const char*)(Bt + (size_t)(t + 1) * 64 * DF);
            char* Bd = Bs[(t + 1) & 1];
            #pragma unroll
            for (int i = 0; i < 4; ++i) {
                int d = (tid + i * 256) * 16;
                int s = d ^ (((d >> 8) & 7) << 4);
                __builtin_amdgcn_global_load_lds((const __attribute__((address_space(1))) void*)(Bb + s),
                                                 (__attribute__((address_space(3))) void*)(Bd + d), 16, 0, 0);
            }
        }
        const char* Bc = Bs[t & 1];
        f32x4 acc[2][2] = {};
        #pragma unroll
        for (int kk = 0; kk < 4; ++kk) {
            int kb = kk * 64 + lkb;
            int ra0 = wm + lr, ra1 = wm + 16 + lr;
            int rb0 = wn + lr, rb1 = wn + 16 + lr;
            bf16x8 a0 = *(const bf16x8*)(As + ((ra0 * 256 + kb) ^ ((ra0 & 7) << 4)));
            bf16x8 a1 = *(const bf16x8*)(As + ((ra1 * 256 + kb) ^ ((ra1 & 7) << 4)));
            bf16x8 b0 = *(const bf16x8*)(Bc + ((rb0 * 256 + kb) ^ ((rb0 & 7) << 4)));
            bf16x8 b1 = *(const bf16x8*)(Bc + ((rb1 * 256 + kb) ^ ((rb1 & 7) << 4)));
            acc[0][0] = __builtin_amdgcn_mfma_f32_16x16x32_bf16(a0, b0, acc[0][0], 0, 0, 0);
            acc[0][1] = __builtin_amdgcn_mfma_f32_16x16x32_bf16(a0, b1, acc[0][1], 0, 0, 0);
            acc[1][0] = __builtin_amdgcn_mfma_f32_16x16x32_bf16(a1, b0, acc[1][0], 0, 0, 0);
            acc[1][1] = __builtin_amdgcn_mfma_f32_16x16x32_bf16(a1, b1, acc[1][1], 0, 0, 0);
        }
        const int n0 = t * 64;
        #pragma unroll
        for (int mi = 0; mi < 2; ++mi) {
            #pragma unroll
            for (int r = 0; r < 4; ++r) {
                int gr = m0 + wm + mi * 16 + orow + r;
                if (gr < M) {
                    #pragma unroll
                    for (int ni = 0; ni < 2; ++ni)
                        Hout[(size_t)gr * HD + n0 + wn + ni * 16 + lr] = __float2bfloat16(acc[mi][ni][r]);
                }
            }
        }
    }
}

// ---------- per-node attention scores: vectorized, 4 nodes / 256-block ----------
__global__ __launch_bounds__(256) void att_scores(const bf16* __restrict__ H,
                                                  const float* __restrict__ as,
                                                  const float* __restrict__ ad,
                                                  float* __restrict__ a_src,
                                                  float* __restrict__ a_dst) {
    const int n = blockIdx.x * 4 + (threadIdx.x >> 6);
    const int l = threadIdx.x & 63;           // lane owns elems l*8..l*8+7 (head = l>>4)
    bf16x8 hv = *reinterpret_cast<const bf16x8*>(H + (size_t)n * HD + l * 8);
    float4 s0 = reinterpret_cast<const float4*>(as)[l * 2];
    float4 s1 = reinterpret_cast<const float4*>(as)[l * 2 + 1];
    float4 d0 = reinterpret_cast<const float4*>(ad)[l * 2];
    float4 d1 = reinterpret_cast<const float4*>(ad)[l * 2 + 1];
    float hf[8];
    #pragma unroll
    for (int j = 0; j < 8; ++j) hf[j] = bf2f(hv[j]);
    float ps = hf[0]*s0.x + hf[1]*s0.y + hf[2]*s0.z + hf[3]*s0.w
             + hf[4]*s1.x + hf[5]*s1.y + hf[6]*s1.z + hf[7]*s1.w;
    float pd = hf[0]*d0.x + hf[1]*d0.y + hf[2]*d0.z + hf[3]*d0.w
             + hf[4]*d1.x + hf[5]*d1.y + hf[6]*d1.z + hf[7]*d1.w;
    #pragma unroll
    for (int off = 1; off < 16; off <<= 1) {
        ps += __shfl_xor(ps, off);
        pd += __shfl_xor(pd, off);
    }
    if ((l & 15) == 0) {
        a_src[n * NH + (l >> 4)] = ps;
        a_dst[n * NH + (l >> 4)] = pd;
    }
}

// ---------- CSR build ----------
__global__ void count_deg(const int* __restrict__ ei, int* __restrict__ counts) {
    int e = blockIdx.x * blockDim.x + threadIdx.x;
    if (e >= ET) return;
    int d = (e < NE) ? ei[NE + e] : (e - NE);
    atomicAdd(&counts[d], 1);
}

__global__ __launch_bounds__(256) void scan1(const int* __restrict__ counts, int* __restrict__ bsum) {
    __shared__ int sd[256];
    int i = blockIdx.x * 256 + threadIdx.x;
    sd[threadIdx.x] = (i < NN) ? counts[i] : 0;
    __syncthreads();
    for (int s = 128; s > 0; s >>= 1) {
        if (threadIdx.x < s) sd[threadIdx.x] += sd[threadIdx.x + s];
        __syncthreads();
    }
    if (threadIdx.x == 0) bsum[blockIdx.x] = sd[0];
}

__global__ void scan2(int* __restrict__ bsum, int nb) {
    if (threadIdx.x == 0 && blockIdx.x == 0) {
        int acc = 0;
        for (int i = 0; i < nb; ++i) { int v = bsum[i]; bsum[i] = acc; acc += v; }
    }
}

__global__ __launch_bounds__(256) void scan3(const int* __restrict__ counts, const int* __restrict__ bsum,
                                             int* __restrict__ row_ptr, int* __restrict__ cursor) {
    __shared__ int sd[256];
    int i = blockIdx.x * 256 + threadIdx.x;
    int v = (i < NN) ? counts[i] : 0;
    sd[threadIdx.x] = v;
    __syncthreads();
    for (int s = 1; s < 256; s <<= 1) {
        int t = sd[threadIdx.x];
        int u = (threadIdx.x >= s) ? sd[threadIdx.x - s] : 0;
        __syncthreads();
        sd[threadIdx.x] = t + u;
        __syncthreads();
    }
    int excl = sd[threadIdx.x] - v + bsum[blockIdx.x];
    if (i < NN) { row_ptr[i] = excl; cursor[i] = excl; }
    if (i == 0) row_ptr[NN] = ET;
}

__global__ void fill_csr(const int* __restrict__ ei, int* __restrict__ cursor, int* __restrict__ col) {
    int e = blockIdx.x * blockDim.x + threadIdx.x;
    if (e >= ET) return;
    int s, d;
    if (e < NE) { s = ei[e]; d = ei[NE + e]; } else { s = d = e - NE; }
    int pos = atomicAdd(&cursor[d], 1);
    col[pos] = s;
}

// ---------- per-edge alpha: one lane per (node, head) ----------
// alpha[4j+h] = fp16( 0.25 * exp(lg - m) / s )
__global__ __launch_bounds__(256) void edge_alpha(const float* __restrict__ a_src,
                                                  const float* __restrict__ a_dst,
                                                  const int* __restrict__ row_ptr,
                                                  const int* __restrict__ col,
                                                  __half* __restrict__ alpha) {
    int t = blockIdx.x * 256 + threadIdx.x;
    int n = t >> 2, h = t & 3;
    if (n >= NN) return;
    const float d = a_dst[n * 4 + h];
    const int start = row_ptr[n], end = row_ptr[n + 1];
    float m = -1e30f, s = 0.f;
    for (int j = start; j < end; ++j) {
        float a = a_src[col[j] * 4 + h] + d;
        a = a > 0.f ? a : 0.2f * a;
        float nm = fmaxf(m, a);
        s = s * __expf(m - nm) + __expf(a - nm);
        m = nm;
    }
    const float inv = 0.25f / s;
    for (int j = start; j < end; ++j) {
        float a = a_src[col[j] * 4 + h] + d;
        a = a > 0.f ? a : 0.2f * a;
        alpha[4 * j + h] = __float2half(__expf(a - m) * inv);
    }
}

// ---------- weighted gather-sum aggregation ----------
// Lane l owns feature bytes 8l..8l+7 of the 512-wide row (head = l>>4); one
// dwordx4 per edge per lane = the wave fetches the full 1024B row coalesced.
// Head-mean via shfl_xor(16,32); lanes 0..15 write the 128 output floats.
#define ACC8(v, a)                                                                  \
    acc[0] += (a) * __uint_as_float((v).x << 16);                                   \
    acc[1] += (a) * __uint_as_float((v).x & 0xffff0000u);                           \
    acc[2] += (a) * __uint_as_float((v).y << 16);                                   \
    acc[3] += (a) * __uint_as_float((v).y & 0xffff0000u);                           \
    acc[4] += (a) * __uint_as_float((v).z << 16);                                   \
    acc[5] += (a) * __uint_as_float((v).z & 0xffff0000u);                           \
    acc[6] += (a) * __uint_as_float((v).w << 16);                                   \
    acc[7] += (a) * __uint_as_float((v).w & 0xffff0000u);

__global__ __launch_bounds__(256) void aggregate(const bf16* __restrict__ H,
                                                 const __half* __restrict__ alpha,
                                                 const int* __restrict__ row_ptr,
                                                 const int* __restrict__ col,
                                                 const float* __restrict__ bias,
                                                 float* __restrict__ out) {
    const int n = blockIdx.x * 4 + (threadIdx.x >> 6);
    const int l = threadIdx.x & 63;
    const int hsel = l >> 4;
    const int start = row_ptr[n], end = row_ptr[n + 1];
    const uint4* __restrict__ H16 = reinterpret_cast<const uint4*>(H);
    float acc[8] = {};
    int j = start;
    for (; j + 4 <= end; j += 4) {
        int c0 = col[j], c1 = col[j + 1], c2 = col[j + 2], c3 = col[j + 3];
        uint4 v0 = H16[(size_t)c0 * 64 + l];
        uint4 v1 = H16[(size_t)c1 * 64 + l];
        uint4 v2 = H16[(size_t)c2 * 64 + l];
        uint4 v3 = H16[(size_t)c3 * 64 + l];
        float a0 = __half2float(alpha[4 * j + hsel]);
        float a1 = __half2float(alpha[4 * (j + 1) + hsel]);
        float a2 = __half2float(alpha[4 * (j + 2) + hsel]);
        float a3 = __half2float(alpha[4 * (j + 3) + hsel]);
        ACC8(v0, a0) ACC8(v1, a1) ACC8(v2, a2) ACC8(v3, a3)
    }
    for (; j < end; ++j) {
        int c0 = col[j];
        uint4 v0 = H16[(size_t)c0 * 64 + l];
        float a0 = __half2float(alpha[4 * j + hsel]);
        ACC8(v0, a0)
    }
    #pragma unroll
    for (int k = 0; k < 8; ++k) {
        acc[k] += __shfl_xor(acc[k], 16);
        acc[k] += __shfl_xor(acc[k], 32);
    }
    if (l < 16) {
        float4 b0 = reinterpret_cast<const float4*>(bias)[l * 2];
        float4 b1 = reinterpret_cast<const float4*>(bias)[l * 2 + 1];
        float4 o0 = make_float4(acc[0] + b0.x, acc[1] + b0.y, acc[2] + b0.z, acc[3] + b0.w);
        float4 o1 = make_float4(acc[4] + b1.x, acc[5] + b1.y, acc[6] + b1.z, acc[7] + b1.w);
        reinterpret_cast<float4*>(out)[(size_t)n * 32 + l * 2] = o0;
        reinterpret_cast<float4*>(out)[(size_t)n * 32 + l * 2 + 1] = o1;
    }
}

// ---------- BatchNorm ----------
__global__ __launch_bounds__(256) void bn_stats(const float* __restrict__ x, float* __restrict__ stats) {
    const int c = threadIdx.x & 127;
    const int half = threadIdx.x >> 7;
    float sum = 0.f, sq = 0.f;
    for (int r = blockIdx.x * 2 + half; r < NN; r += gridDim.x * 2) {
        float v = x[r * DF + c];
        sum += v; sq += v * v;
    }
    __shared__ float s1[256], s2[256];
    s1[threadIdx.x] = sum; s2[threadIdx.x] = sq;
    __syncthreads();
    if (threadIdx.x < 128) {
        atomicAdd(&stats[c], s1[threadIdx.x] + s1[threadIdx.x + 128]);
        atomicAdd(&stats[128 + c], s2[threadIdx.x] + s2[threadIdx.x + 128]);
    }
}

__global__ __launch_bounds__(256) void bn_apply_bf16(const float* __restrict__ x, const float* __restrict__ stats,
                                                     const float* __restrict__ gamma, const float* __restrict__ beta,
                                                     bf16* __restrict__ out) {
    int i = blockIdx.x * blockDim.x + threadIdx.x;
    if (i >= NN * DF) return;
    int c = i & 127;
    float mu = stats[c] * (1.f / NN);
    float var = stats[128 + c] * (1.f / NN) - mu * mu;
    float v = (x[i] - mu) * rsqrtf(var + BN_EPS) * gamma[c] + beta[c];
    out[i] = __float2bfloat16(fmaxf(v, 0.f));
}

__global__ __launch_bounds__(256) void bn_apply(const float* __restrict__ x, const float* __restrict__ stats,
                                                const float* __restrict__ gamma, const float* __restrict__ beta,
                                                float* __restrict__ out) {
    int i = blockIdx.x * blockDim.x + threadIdx.x;
    if (i >= NN * DF) return;
    int c = i & 127;
    float mu = stats[c] * (1.f / NN);
    float var = stats[128 + c] * (1.f / NN) - mu * mu;
    float v = (x[i] - mu) * rsqrtf(var + BN_EPS) * gamma[c] + beta[c];
    out[i] = fmaxf(v, 0.f);
}

extern "C" void kernel_launch(void* const* d_in, const int* in_sizes, int n_in,
                              void* d_out, int out_size, void* d_ws, size_t ws_size,
                              hipStream_t stream) {
    (void)in_sizes; (void)n_in; (void)out_size; (void)ws_size;
    const float* x   = (const float*)d_in[0];
    const int*   ei  = (const int*)d_in[1];
    const float* W1  = (const float*)d_in[2];
    const float* as1 = (const float*)d_in[3];
    const float* ad1 = (const float*)d_in[4];
    const float* b1  = (const float*)d_in[5];
    const float* g1  = (const float*)d_in[6];
    const float* be1 = (const float*)d_in[7];
    const float* W2  = (const float*)d_in[8];
    const float* as2 = (const float*)d_in[9];
    const float* ad2 = (const float*)d_in[10];
    const float* b2  = (const float*)d_in[11];
    const float* g2  = (const float*)d_in[12];
    const float* be2 = (const float*)d_in[13];
    float* out = (float*)d_out;

    char* ws = (char*)d_ws;
    size_t off = 0;
    auto alloc = [&](size_t bytes) -> void* {
        void* p = ws + off;
        off += (bytes + 255) & ~(size_t)255;
        return p;
    };
    bf16*   h       = (bf16*)alloc((size_t)NN * HD * 2);      // 51.2 MB
    bf16*   xb      = (bf16*)alloc((size_t)NP * DF * 2);      // 12.8 MB (padded)
    bf16*   Wt1     = (bf16*)alloc((size_t)HD * DF * 2);
    bf16*   Wt2     = (bf16*)alloc((size_t)HD * DF * 2);
    float*  a_src   = (float*)alloc((size_t)NN * NH * 4);
    float*  a_dst   = (float*)alloc((size_t)NN * NH * 4);
    int*    row_ptr = (int*)alloc((size_t)(NN + 1) * 4);
    int*    cursor  = (int*)alloc((size_t)NN * 4);
    int*    counts  = (int*)alloc((size_t)NN * 4);
    int*    bsum    = (int*)alloc(256 * 4);
    int*    colidx  = (int*)alloc((size_t)ET * 4);
    __half* alpha   = (__half*)alloc((size_t)ET * 8);         // 6.8 MB (fp16 x4 per edge)
    float*  agg     = (float*)alloc((size_t)NN * DF * 4);     // 25.6 MB
    float*  stats   = (float*)alloc(256 * 4);
    // high-water ~102.3 MB (R1 proved >=107.4 MB available)

    const int NB = (NN + 255) / 256;        // 196
    const int EB = (ET + 255) / 256;        // 3321

    // ---- dtype prep + CSR build ----
    cvt_x_bf16<<<(NN * DF / 4 + 255) / 256, 256, 0, stream>>>(x, xb);
    cvt_wt2<<<(2 * HD * DF + 255) / 256, 256, 0, stream>>>(W1, W2, Wt1, Wt2);
    hipMemsetAsync(counts, 0, (size_t)NN * 4, stream);
    count_deg<<<EB, 256, 0, stream>>>(ei, counts);
    scan1<<<NB, 256, 0, stream>>>(counts, bsum);
    scan2<<<1, 64, 0, stream>>>(bsum, NB);
    scan3<<<NB, 256, 0, stream>>>(counts, bsum, row_ptr, cursor);
    fill_csr<<<EB, 256, 0, stream>>>(ei, cursor, colidx);

    // ---- layer 1 ----
    gemm_mfma<<<NP / 64, 256, 0, stream>>>(xb, Wt1, h, NN);
    att_scores<<<NN / 4, 256, 0, stream>>>(h, as1, ad1, a_src, a_dst);
    edge_alpha<<<(NN * 4 + 255) / 256, 256, 0, stream>>>(a_src, a_dst, row_ptr, colidx, alpha);
    aggregate<<<NN / 4, 256, 0, stream>>>(h, alpha, row_ptr, colidx, b1, agg);
    hipMemsetAsync(stats, 0, 256 * 4, stream);
    bn_stats<<<200, 256, 0, stream>>>(agg, stats);
    bn_apply_bf16<<<(NN * DF + 255) / 256, 256, 0, stream>>>(agg, stats, g1, be1, xb);

    // ---- layer 2 ----
    gemm_mfma<<<NP / 64, 256, 0, stream>>>(xb, Wt2, h, NN);
    att_scores<<<NN / 4, 256, 0, stream>>>(h, as2, ad2, a_src, a_dst);
    edge_alpha<<<(NN * 4 + 255) / 256, 256, 0, stream>>>(a_src, a_dst, row_ptr, colidx, alpha);
    aggregate<<<NN / 4, 256, 0, stream>>>(h, alpha, row_ptr, colidx, b2, agg);
    hipMemsetAsync(stats, 0, 256 * 4, stream);
    bn_stats<<<200, 256, 0, stream>>>(agg, stats);
    bn_apply<<<(NN * DF + 255) / 256, 256, 0, stream>>>(agg, stats, g2, be2, out);
}

// Round 7
// 495.600 us; speedup vs baseline: 1.2007x; 1.1490x over previous
//
#include <hip/hip_runtime.h>
#include <hip/hip_bf16.h>
#include <hip/hip_fp16.h>
#include <math.h>

#define NN 50000
#define NP 50048            // NN padded to 64-row tiles
#define NE 800000
#define ET (NE + NN)
#define DF 128
#define NH 4
#define HD 512
#define BN_EPS 1e-5f

typedef __hip_bfloat16 bf16;
typedef __attribute__((ext_vector_type(8))) short bf16x8;
typedef __attribute__((ext_vector_type(4))) float f32x4;

// ---------- input conversions ----------
__global__ __launch_bounds__(256) void cvt_x_bf16(const float* __restrict__ in, bf16* __restrict__ out) {
    int i = blockIdx.x * 256 + threadIdx.x;            // 4 elements per thread
    if (i >= NN * DF / 4) return;
    float4 v = reinterpret_cast<const float4*>(in)[i];
    union { bf16 b[4]; short4 s; } u;
    u.b[0] = __float2bfloat16(v.x); u.b[1] = __float2bfloat16(v.y);
    u.b[2] = __float2bfloat16(v.z); u.b[3] = __float2bfloat16(v.w);
    reinterpret_cast<short4*>(out)[i] = u.s;
}

// wsd[layer][o][d] = sum_c W[d, h*128+c] * att[h][c],  o=h (src, 0..3) or 4+h (dst)
__global__ __launch_bounds__(256) void make_wsd(const float* __restrict__ W1, const float* __restrict__ as1,
                                                const float* __restrict__ ad1,
                                                const float* __restrict__ W2, const float* __restrict__ as2,
                                                const float* __restrict__ ad2,
                                                float* __restrict__ wsd) {
    int t = blockIdx.x * 256 + threadIdx.x;   // 0..2047
    if (t >= 2048) return;
    int layer = t >> 10;
    int o = (t >> 7) & 7;
    int d = t & 127;
    int h = o & 3;
    const float* W  = layer ? W2 : W1;
    const float* av = layer ? (o < 4 ? as2 : ad2) : (o < 4 ? as1 : ad1);
    const float* wrow = W + d * HD + h * DF;
    const float* arow = av + h * DF;
    float sum = 0.f;
    for (int c = 0; c < DF; ++c) sum += wrow[c] * arow[c];
    wsd[layer * 1024 + o * DF + d] = sum;
}

// Bt2[layer][c][h*128+d] = 0.25 * W[d][h*128+c]   (stacked, transposed, head-mean folded)
__global__ __launch_bounds__(256) void cvt_bt2(const float* __restrict__ W1, const float* __restrict__ W2,
                                               bf16* __restrict__ B1, bf16* __restrict__ B2) {
    int i = blockIdx.x * 256 + threadIdx.x;   // 0..131071
    if (i >= 2 * DF * HD) return;
    int layer = i >> 16;
    int ii = i & 65535;
    int c = ii >> 9, k = ii & 511;
    int h = k >> 7, d = k & 127;
    const float* W = layer ? W2 : W1;
    bf16* B = layer ? B2 : B1;
    B[ii] = __float2bfloat16(0.25f * W[d * HD + h * DF + c]);
}

// ---------- per-node scores from x: a[n,o] = <x[n], wsd[o]> ----------
__global__ __launch_bounds__(256) void xscore(const bf16* __restrict__ X,
                                              const float* __restrict__ wsd,   // [8][128]
                                              float* __restrict__ a_src,
                                              float* __restrict__ a_dst) {
    __shared__ float w[8][DF];
    reinterpret_cast<float4*>(&w[0][0])[threadIdx.x] = reinterpret_cast<const float4*>(wsd)[threadIdx.x];
    __syncthreads();
    const int n = blockIdx.x * 4 + (threadIdx.x >> 6);
    const int l = threadIdx.x & 63;          // lane owns features 2l, 2l+1
    unsigned xv = reinterpret_cast<const unsigned*>(X)[n * 64 + l];
    float x0 = __uint_as_float(xv << 16);
    float x1 = __uint_as_float(xv & 0xffff0000u);
    float v[8];
    #pragma unroll
    for (int o = 0; o < 8; ++o)
        v[o] = x0 * w[o][2 * l] + x1 * w[o][2 * l + 1];
    #pragma unroll
    for (int off = 1; off < 64; off <<= 1) {
        #pragma unroll
        for (int o = 0; o < 8; ++o) v[o] += __shfl_xor(v[o], off);
    }
    if (l == 0) {
        reinterpret_cast<float4*>(a_src)[n] = make_float4(v[0], v[1], v[2], v[3]);
        reinterpret_cast<float4*>(a_dst)[n] = make_float4(v[4], v[5], v[6], v[7]);
    }
}

// ---------- CSR build ----------
__global__ void count_deg(const int* __restrict__ ei, int* __restrict__ counts) {
    int e = blockIdx.x * blockDim.x + threadIdx.x;
    if (e >= ET) return;
    int d = (e < NE) ? ei[NE + e] : (e - NE);
    atomicAdd(&counts[d], 1);
}

__global__ __launch_bounds__(256) void scan1(const int* __restrict__ counts, int* __restrict__ bsum) {
    __shared__ int sd[256];
    int i = blockIdx.x * 256 + threadIdx.x;
    sd[threadIdx.x] = (i < NN) ? counts[i] : 0;
    __syncthreads();
    for (int s = 128; s > 0; s >>= 1) {
        if (threadIdx.x < s) sd[threadIdx.x] += sd[threadIdx.x + s];
        __syncthreads();
    }
    if (threadIdx.x == 0) bsum[blockIdx.x] = sd[0];
}

__global__ void scan2(int* __restrict__ bsum, int nb) {
    if (threadIdx.x == 0 && blockIdx.x == 0) {
        int acc = 0;
        for (int i = 0; i < nb; ++i) { int v = bsum[i]; bsum[i] = acc; acc += v; }
    }
}

__global__ __launch_bounds__(256) void scan3(const int* __restrict__ counts, const int* __restrict__ bsum,
                                             int* __restrict__ row_ptr, int* __restrict__ cursor) {
    __shared__ int sd[256];
    int i = blockIdx.x * 256 + threadIdx.x;
    int v = (i < NN) ? counts[i] : 0;
    sd[threadIdx.x] = v;
    __syncthreads();
    for (int s = 1; s < 256; s <<= 1) {
        int t = sd[threadIdx.x];
        int u = (threadIdx.x >= s) ? sd[threadIdx.x - s] : 0;
        __syncthreads();
        sd[threadIdx.x] = t + u;
        __syncthreads();
    }
    int excl = sd[threadIdx.x] - v + bsum[blockIdx.x];
    if (i < NN) { row_ptr[i] = excl; cursor[i] = excl; }
    if (i == 0) row_ptr[NN] = ET;
}

__global__ void fill_csr(const int* __restrict__ ei, int* __restrict__ cursor, int* __restrict__ col) {
    int e = blockIdx.x * blockDim.x + threadIdx.x;
    if (e >= ET) return;
    int s, d;
    if (e < NE) { s = ei[e]; d = ei[NE + e]; } else { s = d = e - NE; }
    int pos = atomicAdd(&cursor[d], 1);
    col[pos] = s;
}

// ---------- per-edge alpha: one lane per (node, head) ----------
__global__ __launch_bounds__(256) void edge_alpha(const float* __restrict__ a_src,
                                                  const float* __restrict__ a_dst,
                                                  const int* __restrict__ row_ptr,
                                                  const int* __restrict__ col,
                                                  __half* __restrict__ alpha) {
    int t = blockIdx.x * 256 + threadIdx.x;
    int n = t >> 2, h = t & 3;
    if (n >= NN) return;
    const float d = a_dst[n * 4 + h];
    const int start = row_ptr[n], end = row_ptr[n + 1];
    float m = -1e30f, s = 0.f;
    for (int j = start; j < end; ++j) {
        float a = a_src[col[j] * 4 + h] + d;
        a = a > 0.f ? a : 0.2f * a;
        float nm = fmaxf(m, a);
        s = s * __expf(m - nm) + __expf(a - nm);
        m = nm;
    }
    const float inv = 1.0f / s;               // head-mean 0.25 folded into Bt2
    for (int j = start; j < end; ++j) {
        float a = a_src[col[j] * 4 + h] + d;
        a = a > 0.f ? a : 0.2f * a;
        alpha[4 * j + h] = __float2half(__expf(a - m) * inv);
    }
}

// ---------- head-weighted x gather: aggX[n][h*128+d] = sum_e alpha[e,h] x[src,d] ----------
#define EDGE(xu, pu) {                                                               \
    float lo = __uint_as_float((xu) << 16);                                          \
    float hi = __uint_as_float((xu) & 0xffff0000u);                                  \
    float2 f01 = __half22float2(*reinterpret_cast<const __half2*>(&(pu).x));         \
    float2 f23 = __half22float2(*reinterpret_cast<const __half2*>(&(pu).y));         \
    acc[0][0] += f01.x * lo; acc[0][1] += f01.x * hi;                                \
    acc[1][0] += f01.y * lo; acc[1][1] += f01.y * hi;                                \
    acc[2][0] += f23.x * lo; acc[2][1] += f23.x * hi;                                \
    acc[3][0] += f23.y * lo; acc[3][1] += f23.y * hi; }

__global__ __launch_bounds__(256) void aggregate_x(const bf16* __restrict__ X,
                                                   const __half* __restrict__ alpha,
                                                   const int* __restrict__ row_ptr,
                                                   const int* __restrict__ col,
                                                   bf16* __restrict__ aggX) {
    const int n = blockIdx.x * 4 + (threadIdx.x >> 6);
    const int l = threadIdx.x & 63;          // lane owns x features 2l, 2l+1
    const int start = row_ptr[n], end = row_ptr[n + 1];
    const unsigned* __restrict__ X4 = reinterpret_cast<const unsigned*>(X);
    float acc[4][2] = {};
    int j = start;
    for (; j + 4 <= end; j += 4) {
        int c0 = col[j], c1 = col[j + 1], c2 = col[j + 2], c3 = col[j + 3];
        unsigned x0 = X4[c0 * 64 + l];
        unsigned x1 = X4[c1 * 64 + l];
        unsigned x2 = X4[c2 * 64 + l];
        unsigned x3 = X4[c3 * 64 + l];
        uint2 p0 = *reinterpret_cast<const uint2*>(alpha + 4 * j);
        uint2 p1 = *reinterpret_cast<const uint2*>(alpha + 4 * (j + 1));
        uint2 p2 = *reinterpret_cast<const uint2*>(alpha + 4 * (j + 2));
        uint2 p3 = *reinterpret_cast<const uint2*>(alpha + 4 * (j + 3));
        EDGE(x0, p0) EDGE(x1, p1) EDGE(x2, p2) EDGE(x3, p3)
    }
    for (; j < end; ++j) {
        unsigned x0 = X4[col[j] * 64 + l];
        uint2 p0 = *reinterpret_cast<const uint2*>(alpha + 4 * j);
        EDGE(x0, p0)
    }
    unsigned* outp = reinterpret_cast<unsigned*>(aggX) + (size_t)n * 256;
    #pragma unroll
    for (int h = 0; h < 4; ++h) {
        union { bf16 b; unsigned short u; } plo, phi;
        plo.b = __float2bfloat16(acc[h][0]);
        phi.b = __float2bfloat16(acc[h][1]);
        outp[h * 64 + l] = (unsigned)plo.u | ((unsigned)phi.u << 16);
    }
}

// ---------- MFMA GEMM: out[M,128](f32) = A[M,512](bf16) @ Bt[128,512]^T + bias ----------
// Grid (NP/64, 2); K=512 in 4 chunks of 128, double-buffered LDS, acc carried.
__global__ __launch_bounds__(256) void gemm_out(const bf16* __restrict__ A,
                                                const bf16* __restrict__ Bt,
                                                const float* __restrict__ bias,
                                                float* __restrict__ out, int M) {
    __shared__ __align__(16) char As[2][16384];   // [64 rows][256B k-chunk], XOR-swizzled
    __shared__ __align__(16) char Bs[2][16384];
    const int tid = threadIdx.x;
    const int m0 = blockIdx.x * 64;
    const int n0 = blockIdx.y * 64;
    const char* Ab = (const char*)A + (size_t)m0 * 1024;     // row stride 512*2 B
    const char* Bb = (const char*)Bt + (size_t)n0 * 1024;
    // stage chunk kc into buffer buf (linear LDS dest + inverse-swizzled strided source)
    auto stage = [&](const char* base, char* lds, int kc) {
        #pragma unroll
        for (int i = 0; i < 4; ++i) {
            int d = (tid + i * 256) * 16;
            int row = d >> 8;
            int s = (d & 255) ^ ((row & 7) << 4);
            __builtin_amdgcn_global_load_lds(
                (const __attribute__((address_space(1))) void*)(base + (size_t)row * 1024 + kc * 256 + s),
                (__attribute__((address_space(3))) void*)(lds + d), 16, 0, 0);
        }
    };
    stage(Ab, As[0], 0);
    stage(Bb, Bs[0], 0);
    const int lane = tid & 63;
    const int wave = tid >> 6;
    const int wm = (wave & 1) * 32;
    const int wn = (wave >> 1) * 32;
    const int lr = lane & 15;
    const int lkb = (lane >> 4) * 16;
    f32x4 acc[2][2] = {};
    for (int kc = 0; kc < 4; ++kc) {
        __syncthreads();                     // staging for chunk kc complete
        if (kc < 3) {
            stage(Ab, As[(kc + 1) & 1], kc + 1);
            stage(Bb, Bs[(kc + 1) & 1], kc + 1);
        }
        const char* Ac = As[kc & 1];
        const char* Bc = Bs[kc & 1];
        #pragma unroll
        for (int kk = 0; kk < 4; ++kk) {
            int kb = kk * 64 + lkb;
            int ra0 = wm + lr, ra1 = wm + 16 + lr;
            int rb0 = wn + lr, rb1 = wn + 16 + lr;
            bf16x8 a0 = *(const bf16x8*)(Ac + ((ra0 * 256 + kb) ^ ((ra0 & 7) << 4)));
            bf16x8 a1 = *(const bf16x8*)(Ac + ((ra1 * 256 + kb) ^ ((ra1 & 7) << 4)));
            bf16x8 b0 = *(const bf16x8*)(Bc + ((rb0 * 256 + kb) ^ ((rb0 & 7) << 4)));
            bf16x8 b1 = *(const bf16x8*)(Bc + ((rb1 * 256 + kb) ^ ((rb1 & 7) << 4)));
            acc[0][0] = __builtin_amdgcn_mfma_f32_16x16x32_bf16(a0, b0, acc[0][0], 0, 0, 0);
            acc[0][1] = __builtin_amdgcn_mfma_f32_16x16x32_bf16(a0, b1, acc[0][1], 0, 0, 0);
            acc[1][0] = __builtin_amdgcn_mfma_f32_16x16x32_bf16(a1, b0, acc[1][0], 0, 0, 0);
            acc[1][1] = __builtin_amdgcn_mfma_f32_16x16x32_bf16(a1, b1, acc[1][1], 0, 0, 0);
        }
    }
    const int orow = (lane >> 4) * 4;
    float bcol[2];
    bcol[0] = bias[n0 + wn + lr];
    bcol[1] = bias[n0 + wn + 16 + lr];
    #pragma unroll
    for (int mi = 0; mi < 2; ++mi) {
        #pragma unroll
        for (int r = 0; r < 4; ++r) {
            int gr = m0 + wm + mi * 16 + orow + r;
            if (gr < M) {
                #pragma unroll
                for (int ni = 0; ni < 2; ++ni)
                    out[(size_t)gr * DF + n0 + wn + ni * 16 + lr] = acc[mi][ni][r] + bcol[ni];
            }
        }
    }
}

// ---------- BatchNorm ----------
__global__ __launch_bounds__(256) void bn_stats(const float* __restrict__ x, float* __restrict__ stats) {
    const int c = threadIdx.x & 127;
    const int half = threadIdx.x >> 7;
    float sum = 0.f, sq = 0.f;
    for (int r = blockIdx.x * 2 + half; r < NN; r += gridDim.x * 2) {
        float v = x[r * DF + c];
        sum += v; sq += v * v;
    }
    __shared__ float s1[256], s2[256];
    s1[threadIdx.x] = sum; s2[threadIdx.x] = sq;
    __syncthreads();
    if (threadIdx.x < 128) {
        atomicAdd(&stats[c], s1[threadIdx.x] + s1[threadIdx.x + 128]);
        atomicAdd(&stats[128 + c], s2[threadIdx.x] + s2[threadIdx.x + 128]);
    }
}

__global__ __launch_bounds__(256) void bn_apply_bf16(const float* __restrict__ x, const float* __restrict__ stats,
                                                     const float* __restrict__ gamma, const float* __restrict__ beta,
                                                     bf16* __restrict__ out) {
    int i = blockIdx.x * blockDim.x + threadIdx.x;
    if (i >= NN * DF) return;
    int c = i & 127;
    float mu = stats[c] * (1.f / NN);
    float var = stats[128 + c] * (1.f / NN) - mu * mu;
    float v = (x[i] - mu) * rsqrtf(var + BN_EPS) * gamma[c] + beta[c];
    out[i] = __float2bfloat16(fmaxf(v, 0.f));
}

__global__ __launch_bounds__(256) void bn_apply(const float* __restrict__ x, const float* __restrict__ stats,
                                                const float* __restrict__ gamma, const float* __restrict__ beta,
                                                float* __restrict__ out) {
    int i = blockIdx.x * blockDim.x + threadIdx.x;
    if (i >= NN * DF) return;
    int c = i & 127;
    float mu = stats[c] * (1.f / NN);
    float var = stats[128 + c] * (1.f / NN) - mu * mu;
    float v = (x[i] - mu) * rsqrtf(var + BN_EPS) * gamma[c] + beta[c];
    out[i] = fmaxf(v, 0.f);
}

extern "C" void kernel_launch(void* const* d_in, const int* in_sizes, int n_in,
                              void* d_out, int out_size, void* d_ws, size_t ws_size,
                              hipStream_t stream) {
    (void)in_sizes; (void)n_in; (void)out_size; (void)ws_size;
    const float* x   = (const float*)d_in[0];
    const int*   ei  = (const int*)d_in[1];
    const float* W1  = (const float*)d_in[2];
    const float* as1 = (const float*)d_in[3];
    const float* ad1 = (const float*)d_in[4];
    const float* b1  = (const float*)d_in[5];
    const float* g1  = (const float*)d_in[6];
    const float* be1 = (const float*)d_in[7];
    const float* W2  = (const float*)d_in[8];
    const float* as2 = (const float*)d_in[9];
    const float* ad2 = (const float*)d_in[10];
    const float* b2  = (const float*)d_in[11];
    const float* g2  = (const float*)d_in[12];
    const float* be2 = (const float*)d_in[13];
    float* out = (float*)d_out;

    char* ws = (char*)d_ws;
    size_t off = 0;
    auto alloc = [&](size_t bytes) -> void* {
        void* p = ws + off;
        off += (bytes + 255) & ~(size_t)255;
        return p;
    };
    bf16*   aggX    = (bf16*)alloc((size_t)NP * HD * 2);      // 51.25 MB
    bf16*   xb      = (bf16*)alloc((size_t)NP * DF * 2);      // 12.8 MB (padded)
    bf16*   Bt2a    = (bf16*)alloc((size_t)DF * HD * 2);      // 128 KB
    bf16*   Bt2b    = (bf16*)alloc((size_t)DF * HD * 2);
    float*  wsd     = (float*)alloc(2 * 1024 * 4);            // 8 KB
    float*  a_src   = (float*)alloc((size_t)NN * NH * 4);
    float*  a_dst   = (float*)alloc((size_t)NN * NH * 4);
    int*    row_ptr = (int*)alloc((size_t)(NN + 1) * 4);
    int*    cursor  = (int*)alloc((size_t)NN * 4);
    int*    counts  = (int*)alloc((size_t)NN * 4);
    int*    bsum    = (int*)alloc(256 * 4);
    int*    colidx  = (int*)alloc((size_t)ET * 4);
    __half* alpha   = (__half*)alloc((size_t)ET * 8);         // 6.8 MB
    float*  agg     = (float*)alloc((size_t)NN * DF * 4);     // 25.6 MB
    float*  stats   = (float*)alloc(256 * 4);
    // high-water ~102 MB (<= R1-proven 107.4 MB)

    const int NB = (NN + 255) / 256;        // 196
    const int EB = (ET + 255) / 256;        // 3321
    dim3 ogrid(NP / 64, 2);                 // 782 x 2

    // ---- prep + CSR build ----
    cvt_x_bf16<<<(NN * DF / 4 + 255) / 256, 256, 0, stream>>>(x, xb);
    make_wsd<<<8, 256, 0, stream>>>(W1, as1, ad1, W2, as2, ad2, wsd);
    cvt_bt2<<<(2 * DF * HD + 255) / 256, 256, 0, stream>>>(W1, W2, Bt2a, Bt2b);
    hipMemsetAsync(counts, 0, (size_t)NN * 4, stream);
    count_deg<<<EB, 256, 0, stream>>>(ei, counts);
    scan1<<<NB, 256, 0, stream>>>(counts, bsum);
    scan2<<<1, 64, 0, stream>>>(bsum, NB);
    scan3<<<NB, 256, 0, stream>>>(counts, bsum, row_ptr, cursor);
    fill_csr<<<EB, 256, 0, stream>>>(ei, cursor, colidx);

    // ---- layer 1 ----
    xscore<<<NN / 4, 256, 0, stream>>>(xb, wsd, a_src, a_dst);
    edge_alpha<<<(NN * 4 + 255) / 256, 256, 0, stream>>>(a_src, a_dst, row_ptr, colidx, alpha);
    aggregate_x<<<NN / 4, 256, 0, stream>>>(xb, alpha, row_ptr, colidx, aggX);
    gemm_out<<<ogrid, 256, 0, stream>>>(aggX, Bt2a, b1, agg, NN);
    hipMemsetAsync(stats, 0, 256 * 4, stream);
    bn_stats<<<200, 256, 0, stream>>>(agg, stats);
    bn_apply_bf16<<<(NN * DF + 255) / 256, 256, 0, stream>>>(agg, stats, g1, be1, xb);

    // ---- layer 2 ----
    xscore<<<NN / 4, 256, 0, stream>>>(xb, wsd + 1024, a_src, a_dst);
    edge_alpha<<<(NN * 4 + 255) / 256, 256, 0, stream>>>(a_src, a_dst, row_ptr, colidx, alpha);
    aggregate_x<<<NN / 4, 256, 0, stream>>>(xb, alpha, row_ptr, colidx, aggX);
    gemm_out<<<ogrid, 256, 0, stream>>>(aggX, Bt2b, b2, agg, NN);
    hipMemsetAsync(stats, 0, 256 * 4, stream);
    bn_stats<<<200, 256, 0, stream>>>(agg, stats);
    bn_apply<<<(NN * DF + 255) / 256, 256, 0, stream>>>(agg, stats, g2, be2, out);
}